// Round 7
// baseline (273.662 us; speedup 1.0000x reference)
//
#include <hip/hip_runtime.h>
#include <math.h>

#define BB 16
#define HH 256
#define WW 256
#define NN (BB*HH*WW)
#define STH 4        // sobel rows per block
#define SCAN_INIT 300

static __device__ constexpr float INF_EDT = 131072.0f; // H*H + W*W, exact in fp32

__device__ __forceinline__ float sigmoidf(float v){ return 1.0f/(1.0f+expf(-v)); }
// stable log_sigmoid(v) = min(v,0) - log1p(exp(-|v|))
__device__ __forceinline__ float logsigf(float v){
  return fminf(v, 0.0f) - log1pf(expf(-fabsf(v)));
}
__device__ __forceinline__ float min3f(float a, float b, float c){
  return fminf(fminf(a, b), c);   // clang fuses to v_min3_f32
}

__global__ void init_ws_k(float* __restrict__ acc, int* __restrict__ has_pos){
  int t = threadIdx.x;
  if (t < 8)  acc[t] = 0.0f;
  if (t < BB) has_pos[t] = 0;
}

// -------------------------------------------------------------------------
// Column EDT via forward/backward scan (exact for binary seeds).
// g(x,j) = min_i f(i,j)+(x-i)^2 = Dcol(x,j)^2 where Dcol = distance to the
// nearest seed in column j (if the column has a seed), else 131072 exactly
// (the brute force yields INF + 0 choosing i=x). Integers -> fp32 exact,
// bit-identical to the reference brute force.
// One wave per 64 columns; thread = column. Loads/stores coalesced per row.
// -------------------------------------------------------------------------
__global__ __launch_bounds__(64) void edt_cols_scan(const float* __restrict__ tgt,
                                                    float* __restrict__ gA,
                                                    float* __restrict__ gB,
                                                    int* __restrict__ has_pos){
  __shared__ unsigned int fwd_s[HH*64];   // packed (dp<<16)|dn per row
  const int b  = blockIdx.x >> 2;
  const int j0 = (blockIdx.x & 3) << 6;
  const int l  = threadIdx.x;
  const int j  = j0 + l;

  int dp = SCAN_INIT, dn = SCAN_INIT;
  bool col_p = false, col_n = false;
  #pragma unroll 4
  for (int i = 0; i < HH; ++i){
    const float tv = tgt[(b*HH + i)*WW + j];
    const bool s = tv > 0.5f;
    dp = s ? 0 : dp + 1;          // dist to nearest pos seed above (incl self)
    dn = s ? dn + 1 : 0;          // dist to nearest neg seed above (incl self)
    col_p |= s; col_n |= !s;
    fwd_s[i*64 + l] = ((unsigned)dp << 16) | (unsigned)dn;
  }
  unsigned long long bal = __ballot(col_p);
  if (l == 0 && bal) atomicOr(&has_pos[b], 1);

  int bp = SCAN_INIT, bn = SCAN_INIT;
  #pragma unroll 4
  for (int i = HH-1; i >= 0; --i){
    const unsigned f = fwd_s[i*64 + l];   // own column only -> no sync needed
    const int fp = (int)(f >> 16), fn = (int)(f & 0xffffu);
    bp = (fp == 0) ? 0 : bp + 1;          // fp==0 iff seed at (i,j)
    bn = (fn == 0) ? 0 : bn + 1;
    const int Dp = min(fp, bp), Dn = min(fn, bn);
    const int o = (b*HH + i)*WW + j;
    gA[o] = col_p ? (float)(Dp*Dp) : INF_EDT;
    gB[o] = col_n ? (float)(Dn*Dn) : INF_EDT;
  }
}

// -------------------------------------------------------------------------
// Pass 2: d2(x,y) = min_j g(x,j) + (y-j)^2, windowed: since j=y gives
// candidate g(x,y), any j with (y-j)^2 > g(x,y) cannot win -> search only
// |y-j| <= sqrt(g(x,y)). Clamped edge indices give overestimated candidates
// (real g + larger dj^2) -> never undercut the exact min. Fused loss epilogue.
// -------------------------------------------------------------------------
__global__ __launch_bounds__(256) void edt_pass2_fused(const float* __restrict__ inp,
    const float* __restrict__ tgt, const float* __restrict__ gA, const float* __restrict__ gB,
    const int* __restrict__ has_pos, float* __restrict__ acc){
  __shared__ __align__(16) float ga_s[WW];
  __shared__ __align__(16) float gb_s[WW];
  __shared__ float red[3][4];
  const int b = blockIdx.x >> 8;
  const int x = blockIdx.x & 255;
  const int t = threadIdx.x;      // = y
  const int rowbase = (b*HH + x)*WW;
  ga_s[t] = gA[rowbase + t];
  gb_s[t] = gB[rowbase + t];
  __syncthreads();

  const int y = t;
  float dp = ga_s[y];
  float dn = gb_s[y];
  {
    int wp = (int)sqrtf(dp) + 1; if (wp > 255) wp = 255;
    for (int dj = 1; dj <= wp; ++dj){
      const float d2 = (float)(dj*dj);
      const int jl = (y - dj) < 0   ? 0   : y - dj;
      const int jr = (y + dj) > 255 ? 255 : y + dj;
      dp = min3f(dp, ga_s[jl] + d2, ga_s[jr] + d2);
    }
  }
  {
    int wn = (int)sqrtf(dn) + 1; if (wn > 255) wn = 255;
    for (int dj = 1; dj <= wn; ++dj){
      const float d2 = (float)(dj*dj);
      const int jl = (y - dj) < 0   ? 0   : y - dj;
      const int jr = (y + dj) > 255 ? 255 : y + dj;
      dn = min3f(dn, gb_s[jl] + d2, gb_s[jr] + d2);
    }
  }

  // fused focal / ce / boundary
  const float xv = inp[rowbase + y];
  const float tv = tgt[rowbase + y];
  const float sg = sigmoidf(xv);
  float sdf = sqrtf(dn) - sqrtf(dp);     // d_out - d_in
  sdf = has_pos[b] ? sdf : 0.0f;
  float s2 = (sg - tv) * sdf;
  const float lp = logsigf(xv);
  const float ln = logsigf(-xv);
  const float bce = -(tv*lp + (1.0f - tv)*ln);
  const float pt = expf(-bce);
  const float om = 1.0f - pt;
  float s0 = 0.8f * om * om * bce;       // ALPHA=0.8, GAMMA=2
  float s1 = bce;                        // ce with POS_W=1 == bce

  #pragma unroll
  for (int o = 32; o > 0; o >>= 1){
    s0 += __shfl_down(s0, o);
    s1 += __shfl_down(s1, o);
    s2 += __shfl_down(s2, o);
  }
  const int w = t >> 6, l = t & 63;
  if (l == 0){ red[0][w]=s0; red[1][w]=s1; red[2][w]=s2; }
  __syncthreads();
  if (t == 0){
    atomicAdd(&acc[0], red[0][0]+red[0][1]+red[0][2]+red[0][3]);
    atomicAdd(&acc[1], red[1][0]+red[1][1]+red[1][2]+red[1][3]);
    atomicAdd(&acc[2], red[2][0]+red[2][1]+red[2][2]+red[2][3]);
  }
}

// Sobel edge term: mean |S(sigmoid(x)) - S(t)| with replicate padding.
__global__ __launch_bounds__(256) void sobel_edge_k(const float* __restrict__ inp,
    const float* __restrict__ tgt, float* __restrict__ acc){
  __shared__ __align__(16) float ss[STH+2][WW];
  __shared__ __align__(16) float tt[STH+2][WW];
  __shared__ float red[4];
  const int b  = blockIdx.x >> 6;            // H/STH = 64 strips per image
  const int r0 = (blockIdx.x & 63) * STH;
  const int t  = threadIdx.x;
  const int g = t >> 6, l = t & 63;

  for (int k = g; k < STH+2; k += 4){
    int gr = r0 - 1 + k; gr = gr < 0 ? 0 : (gr > HH-1 ? HH-1 : gr);
    const float4 xv = *(const float4*)&inp[(b*HH + gr)*WW + 4*l];
    const float4 tv = *(const float4*)&tgt[(b*HH + gr)*WW + 4*l];
    float4 sv; sv.x = sigmoidf(xv.x); sv.y = sigmoidf(xv.y);
    sv.z = sigmoidf(xv.z); sv.w = sigmoidf(xv.w);
    *(float4*)&ss[k][4*l] = sv;
    *(float4*)&tt[k][4*l] = tv;
  }
  __syncthreads();

  const int c = t;
  const int cm = c ? c-1 : 0, cp = c < WW-1 ? c+1 : WW-1;
  float a0m = ss[0][cm], a0c = ss[0][c], a0p = ss[0][cp];
  float a1m = ss[1][cm], a1c = ss[1][c], a1p = ss[1][cp];
  float b0m = tt[0][cm], b0c = tt[0][c], b0p = tt[0][cp];
  float b1m = tt[1][cm], b1c = tt[1][c], b1p = tt[1][cp];
  float v = 0.0f;
  #pragma unroll
  for (int rr = 0; rr < STH; ++rr){
    const float a2m = ss[rr+2][cm], a2c = ss[rr+2][c], a2p = ss[rr+2][cp];
    const float b2m = tt[rr+2][cm], b2c = tt[rr+2][c], b2p = tt[rr+2][cp];
    const float gxs = ((a0p-a0m) + 2.0f*(a1p-a1m) + (a2p-a2m)) * 0.125f;
    const float gys = ((a2m-a0m) + 2.0f*(a2c-a0c) + (a2p-a0p)) * 0.125f;
    const float mags = sqrtf(gxs*gxs + gys*gys + 1e-6f);
    const float gxt = ((b0p-b0m) + 2.0f*(b1p-b1m) + (b2p-b2m)) * 0.125f;
    const float gyt = ((b2m-b0m) + 2.0f*(b2c-b0c) + (b2p-b0p)) * 0.125f;
    const float magt = sqrtf(gxt*gxt + gyt*gyt + 1e-6f);
    v += fabsf(mags - magt);
    a0m=a1m; a0c=a1c; a0p=a1p; a1m=a2m; a1c=a2c; a1p=a2p;
    b0m=b1m; b0c=b1c; b0p=b1p; b1m=b2m; b1c=b2c; b1p=b2p;
  }
  #pragma unroll
  for (int o = 32; o > 0; o >>= 1) v += __shfl_down(v, o);
  if (l == 0) red[g] = v;
  __syncthreads();
  if (t == 0) atomicAdd(&acc[3], red[0]+red[1]+red[2]+red[3]);
}

__global__ void finalize_k(const float* __restrict__ acc, float* __restrict__ out){
  out[0] = (acc[0] + acc[1] + acc[2] + acc[3]) * (1.0f/(float)NN);
}

extern "C" void kernel_launch(void* const* d_in, const int* in_sizes, int n_in,
                              void* d_out, int out_size, void* d_ws, size_t ws_size,
                              hipStream_t stream){
  const float* inp = (const float*)d_in[0];
  const float* tgt = (const float*)d_in[1];
  float* out = (float*)d_out;
  float* gA  = (float*)d_ws;          // B*H*W fp32, seeds = pos
  float* gB  = gA + NN;               // B*H*W fp32, seeds = ~pos
  float* acc = gB + NN;               // [focal, ce(bce), boundary, edge]
  int* has_pos = (int*)(acc + 8);     // B ints

  init_ws_k<<<1, 64, 0, stream>>>(acc, has_pos);
  edt_cols_scan<<<BB*4, 64, 0, stream>>>(tgt, gA, gB, has_pos);
  edt_pass2_fused<<<BB*HH, 256, 0, stream>>>(inp, tgt, gA, gB, has_pos, acc);
  sobel_edge_k<<<BB*(HH/STH), 256, 0, stream>>>(inp, tgt, acc);
  finalize_k<<<1, 1, 0, stream>>>(acc, out);
}

// Round 8
// 108.303 us; speedup vs baseline: 2.5268x; 2.5268x over previous
//
#include <hip/hip_runtime.h>
#include <math.h>

#define BB 16
#define HH 256
#define WW 256
#define NN (BB*HH*WW)
#define STH 4        // sobel rows per block
#define SCAN_INIT 300
#define BIGR 100000

static __device__ constexpr float INF_EDT = 131072.0f; // H*H + W*W, exact in fp32

__device__ __forceinline__ float sigmoidf(float v){ return 1.0f/(1.0f+expf(-v)); }
// stable log_sigmoid(v) = min(v,0) - log1p(exp(-|v|))
__device__ __forceinline__ float logsigf(float v){
  return fminf(v, 0.0f) - log1pf(expf(-fabsf(v)));
}
__device__ __forceinline__ float min3f(float a, float b, float c){
  return fminf(fminf(a, b), c);   // clang fuses to v_min3_f32
}

__global__ void init_ws_k(int* __restrict__ has_pos){
  int t = threadIdx.x;
  if (t < BB) has_pos[t] = 0;
}

// -------------------------------------------------------------------------
// Column EDT, segmented scan (exact for binary seeds).
// g(x,j) = Dcol(x,j)^2 where Dcol = dist to nearest seed in column j, or
// 131072 exactly if the column has none (brute force: INF + 0 at i=x).
// Block = 256 thr (4 waves) x 64 columns; wave w scans rows [64w,64w+64).
// Cross-segment seeds handled via per-segment first/last seed rows:
// nearest seed above segment = max(last[s<w]); below = min(first[s>w]).
// Integer-valued fp32 -> bit-identical to the reference brute force.
// -------------------------------------------------------------------------
__global__ __launch_bounds__(256) void edt_cols_scan(const float* __restrict__ tgt,
                                                     float* __restrict__ gA,
                                                     float* __restrict__ gB,
                                                     int* __restrict__ has_pos){
  __shared__ unsigned int fwd_s[HH*64];   // [row][lane]: packed (dp<<16)|dn, seg-local fwd
  __shared__ int lastp_s[4][64], firstp_s[4][64];
  __shared__ int lastn_s[4][64], firstn_s[4][64];
  const int b  = blockIdx.x >> 2;
  const int j0 = (blockIdx.x & 3) << 6;
  const int w  = threadIdx.x >> 6;
  const int l  = threadIdx.x & 63;
  const int j  = j0 + l;
  const int r0 = w << 6;

  int dp = SCAN_INIT, dn = SCAN_INIT;
  int firstp = BIGR, lastp = -BIGR, firstn = BIGR, lastn = -BIGR;
  #pragma unroll 4
  for (int i = 0; i < 64; ++i){
    const int gi = r0 + i;
    const float tv = tgt[(b*HH + gi)*WW + j];
    const bool s = tv > 0.5f;
    dp = s ? 0 : dp + 1;
    dn = s ? dn + 1 : 0;
    if (s){ lastp = gi; if (firstp == BIGR) firstp = gi; }
    else  { lastn = gi; if (firstn == BIGR) firstn = gi; }
    fwd_s[gi*64 + l] = ((unsigned)dp << 16) | (unsigned)dn;
  }
  lastp_s[w][l] = lastp; firstp_s[w][l] = firstp;
  lastn_s[w][l] = lastn; firstn_s[w][l] = firstn;
  __syncthreads();

  // cross-segment nearest-seed rows for this wave's segment
  int upP = -BIGR, dnP = BIGR, upN = -BIGR, dnN = BIGR;
  int allLastP = -BIGR, allLastN = -BIGR;
  #pragma unroll
  for (int s = 0; s < 4; ++s){
    const int lp = lastp_s[s][l], fp = firstp_s[s][l];
    const int ln = lastn_s[s][l], fn = firstn_s[s][l];
    allLastP = max(allLastP, lp); allLastN = max(allLastN, ln);
    if (s < w){ upP = max(upP, lp); upN = max(upN, ln); }
    if (s > w){ dnP = min(dnP, fp); dnN = min(dnN, fn); }
  }
  const bool colp = allLastP >= 0;
  const bool coln = allLastN >= 0;
  if (w == 0){
    unsigned long long bal = __ballot(colp);
    if (l == 0 && bal) atomicOr(&has_pos[b], 1);
  }

  int bp = SCAN_INIT, bn = SCAN_INIT;
  #pragma unroll 4
  for (int i = 63; i >= 0; --i){
    const int gi = r0 + i;
    const unsigned f = fwd_s[gi*64 + l];
    const int fp = (int)(f >> 16), fn = (int)(f & 0xffffu);
    bp = (fp == 0) ? 0 : bp + 1;
    bn = (fn == 0) ? 0 : bn + 1;
    int Dp = min(min(fp, bp), min(gi - upP, dnP - gi));
    int Dn = min(min(fn, bn), min(gi - upN, dnN - gi));
    Dp = min(Dp, 512); Dn = min(Dn, 512);   // never binds when col has a seed
    const int o = (b*HH + gi)*WW + j;
    gA[o] = colp ? (float)(Dp*Dp) : INF_EDT;
    gB[o] = coln ? (float)(Dn*Dn) : INF_EDT;
  }
}

// -------------------------------------------------------------------------
// Pass 2: d2(x,y) = min_j g(x,j) + (y-j)^2, windowed: j=y gives candidate
// g(x,y), so only |y-j| <= sqrt(g(x,y)) can improve. Unrolled by 4 with
// clamp-overrun: extra candidates are g(x,jl)+dj^2 with dj >= |y-jl| ->
// always >= the true min (never undercut). 4 rows per block; partial sums
// written to dedicated slots (NO contended atomics). Fused loss epilogue.
// -------------------------------------------------------------------------
__global__ __launch_bounds__(256) void edt_pass2_fused(const float* __restrict__ inp,
    const float* __restrict__ tgt, const float* __restrict__ gA, const float* __restrict__ gB,
    const int* __restrict__ has_pos,
    float* __restrict__ pf, float* __restrict__ pb, float* __restrict__ pbd){
  __shared__ __align__(16) float ga_s[4][WW];
  __shared__ __align__(16) float gb_s[4][WW];
  __shared__ float red[3][4];
  const int b  = blockIdx.x >> 6;
  const int x0 = (blockIdx.x & 63) << 2;
  const int t  = threadIdx.x;

  {
    const int q = t >> 6, l4 = (t & 63) << 2;
    const int base = (b*HH + x0 + q)*WW + l4;
    *(float4*)&ga_s[q][l4] = *(const float4*)&gA[base];
    *(float4*)&gb_s[q][l4] = *(const float4*)&gB[base];
  }
  __syncthreads();

  const int y = t;
  const int hp_ = has_pos[b];
  float s0 = 0.0f, s1 = 0.0f, s2 = 0.0f;   // focal, bce, boundary
  #pragma unroll
  for (int r = 0; r < 4; ++r){
    float dp = ga_s[r][y];
    float dn = gb_s[r][y];
    int wm = (int)sqrtf(fmaxf(dp, dn)) + 1; if (wm > 255) wm = 255;
    for (int dj = 1; dj <= wm; dj += 4){
      #pragma unroll
      for (int u = 0; u < 4; ++u){
        const int d = dj + u;
        const float d2 = (float)(d*d);
        const int jl = (y - d) < 0   ? 0   : y - d;
        const int jr = (y + d) > 255 ? 255 : y + d;
        dp = min3f(dp, ga_s[r][jl] + d2, ga_s[r][jr] + d2);
        dn = min3f(dn, gb_s[r][jl] + d2, gb_s[r][jr] + d2);
      }
    }
    const int o = (b*HH + x0 + r)*WW + y;
    const float xv = inp[o];
    const float tv = tgt[o];
    const float sg = sigmoidf(xv);
    float sdf = sqrtf(dn) - sqrtf(dp);     // d_out - d_in
    sdf = hp_ ? sdf : 0.0f;
    s2 += (sg - tv) * sdf;
    const float lp = logsigf(xv);
    const float ln = logsigf(-xv);
    const float bce = -(tv*lp + (1.0f - tv)*ln);
    const float pt = expf(-bce);
    const float om = 1.0f - pt;
    s0 += 0.8f * om * om * bce;            // ALPHA=0.8, GAMMA=2
    s1 += bce;                             // ce with POS_W=1 == bce
  }

  #pragma unroll
  for (int o = 32; o > 0; o >>= 1){
    s0 += __shfl_down(s0, o);
    s1 += __shfl_down(s1, o);
    s2 += __shfl_down(s2, o);
  }
  const int w = t >> 6, l = t & 63;
  if (l == 0){ red[0][w]=s0; red[1][w]=s1; red[2][w]=s2; }
  __syncthreads();
  if (t == 0){
    pf [blockIdx.x] = red[0][0]+red[0][1]+red[0][2]+red[0][3];
    pb [blockIdx.x] = red[1][0]+red[1][1]+red[1][2]+red[1][3];
    pbd[blockIdx.x] = red[2][0]+red[2][1]+red[2][2]+red[2][3];
  }
}

// Sobel edge term: mean |S(sigmoid(x)) - S(t)| with replicate padding.
__global__ __launch_bounds__(256) void sobel_edge_k(const float* __restrict__ inp,
    const float* __restrict__ tgt, float* __restrict__ pe){
  __shared__ __align__(16) float ss[STH+2][WW];
  __shared__ __align__(16) float tt[STH+2][WW];
  __shared__ float red[4];
  const int b  = blockIdx.x >> 6;            // H/STH = 64 strips per image
  const int r0 = (blockIdx.x & 63) * STH;
  const int t  = threadIdx.x;
  const int g = t >> 6, l = t & 63;

  for (int k = g; k < STH+2; k += 4){
    int gr = r0 - 1 + k; gr = gr < 0 ? 0 : (gr > HH-1 ? HH-1 : gr);
    const float4 xv = *(const float4*)&inp[(b*HH + gr)*WW + 4*l];
    const float4 tv = *(const float4*)&tgt[(b*HH + gr)*WW + 4*l];
    float4 sv; sv.x = sigmoidf(xv.x); sv.y = sigmoidf(xv.y);
    sv.z = sigmoidf(xv.z); sv.w = sigmoidf(xv.w);
    *(float4*)&ss[k][4*l] = sv;
    *(float4*)&tt[k][4*l] = tv;
  }
  __syncthreads();

  const int c = t;
  const int cm = c ? c-1 : 0, cp = c < WW-1 ? c+1 : WW-1;
  float a0m = ss[0][cm], a0c = ss[0][c], a0p = ss[0][cp];
  float a1m = ss[1][cm], a1c = ss[1][c], a1p = ss[1][cp];
  float b0m = tt[0][cm], b0c = tt[0][c], b0p = tt[0][cp];
  float b1m = tt[1][cm], b1c = tt[1][c], b1p = tt[1][cp];
  float v = 0.0f;
  #pragma unroll
  for (int rr = 0; rr < STH; ++rr){
    const float a2m = ss[rr+2][cm], a2c = ss[rr+2][c], a2p = ss[rr+2][cp];
    const float b2m = tt[rr+2][cm], b2c = tt[rr+2][c], b2p = tt[rr+2][cp];
    const float gxs = ((a0p-a0m) + 2.0f*(a1p-a1m) + (a2p-a2m)) * 0.125f;
    const float gys = ((a2m-a0m) + 2.0f*(a2c-a0c) + (a2p-a0p)) * 0.125f;
    const float mags = sqrtf(gxs*gxs + gys*gys + 1e-6f);
    const float gxt = ((b0p-b0m) + 2.0f*(b1p-b1m) + (b2p-b2m)) * 0.125f;
    const float gyt = ((b2m-b0m) + 2.0f*(b2c-b0c) + (b2p-b0p)) * 0.125f;
    const float magt = sqrtf(gxt*gxt + gyt*gyt + 1e-6f);
    v += fabsf(mags - magt);
    a0m=a1m; a0c=a1c; a0p=a1p; a1m=a2m; a1c=a2c; a1p=a2p;
    b0m=b1m; b0c=b1c; b0p=b1p; b1m=b2m; b1c=b2c; b1p=b2p;
  }
  #pragma unroll
  for (int o = 32; o > 0; o >>= 1) v += __shfl_down(v, o);
  if (l == 0) red[g] = v;
  __syncthreads();
  if (t == 0) pe[blockIdx.x] = red[0]+red[1]+red[2]+red[3];
}

// Sum all 4096 partials (1024 each: focal, bce, boundary, edge) -> out.
__global__ __launch_bounds__(256) void finalize_k(const float* __restrict__ part,
                                                  float* __restrict__ out){
  __shared__ float red[4];
  const int t = threadIdx.x;
  float s = 0.0f;
  #pragma unroll
  for (int i = t; i < 4096; i += 256) s += part[i];
  #pragma unroll
  for (int o = 32; o > 0; o >>= 1) s += __shfl_down(s, o);
  if ((t & 63) == 0) red[t >> 6] = s;
  __syncthreads();
  if (t == 0) out[0] = (red[0]+red[1]+red[2]+red[3]) * (1.0f/(float)NN);
}

extern "C" void kernel_launch(void* const* d_in, const int* in_sizes, int n_in,
                              void* d_out, int out_size, void* d_ws, size_t ws_size,
                              hipStream_t stream){
  const float* inp = (const float*)d_in[0];
  const float* tgt = (const float*)d_in[1];
  float* out = (float*)d_out;
  float* gA   = (float*)d_ws;         // B*H*W fp32, seeds = pos
  float* gB   = gA + NN;              // B*H*W fp32, seeds = ~pos
  float* part = gB + NN;              // 4096 partials: [pf 1024][pb 1024][pbd 1024][pe 1024]
  float* pf   = part;
  float* pb   = part + 1024;
  float* pbd  = part + 2048;
  float* pe   = part + 3072;
  int* has_pos = (int*)(part + 4096); // B ints

  init_ws_k<<<1, 64, 0, stream>>>(has_pos);
  edt_cols_scan<<<BB*4, 256, 0, stream>>>(tgt, gA, gB, has_pos);
  edt_pass2_fused<<<BB*(HH/4), 256, 0, stream>>>(inp, tgt, gA, gB, has_pos, pf, pb, pbd);
  sobel_edge_k<<<BB*(HH/STH), 256, 0, stream>>>(inp, tgt, pe);
  finalize_k<<<1, 256, 0, stream>>>(part, out);
}

// Round 9
// 93.064 us; speedup vs baseline: 2.9406x; 1.1637x over previous
//
#include <hip/hip_runtime.h>
#include <math.h>

#define BB 16
#define HH 256
#define WW 256
#define NN (BB*HH*WW)
#define SCAN_INIT 300
#define BIGR 100000

static __device__ constexpr float INF_EDT = 131072.0f; // H*H + W*W, exact in fp32

__device__ __forceinline__ float sigmoidf(float v){ return 1.0f/(1.0f+expf(-v)); }
// stable log_sigmoid(v) = min(v,0) - log1p(exp(-|v|))
__device__ __forceinline__ float logsigf(float v){
  return fminf(v, 0.0f) - log1pf(expf(-fabsf(v)));
}
__device__ __forceinline__ float min3f(float a, float b, float c){
  return fminf(fminf(a, b), c);   // clang fuses to v_min3_f32
}

// -------------------------------------------------------------------------
// Column EDT, segmented scan (exact for binary seeds).
// g(x,j) = Dcol(x,j)^2, Dcol = dist to nearest seed in column j, or 131072
// exactly if the column has none (brute force: INF + 0 at i=x).
// Block = 512 thr (8 waves) x 64 columns; wave w scans rows [32w, 32w+32).
// Cross-segment: nearest seed above = max(last[s<w]), below = min(first[s>w]).
// hp_blk[blockIdx] = any pos in this block's 64 columns (no atomics, no init).
// Integer-valued fp32 -> bit-identical to the reference brute force.
// -------------------------------------------------------------------------
__global__ __launch_bounds__(512) void edt_cols_scan(const float* __restrict__ tgt,
                                                     float* __restrict__ gA,
                                                     float* __restrict__ gB,
                                                     int* __restrict__ hp_blk){
  __shared__ unsigned int fwd_s[HH*64];   // [row][lane]: packed (dp<<16)|dn
  __shared__ int lastp_s[8][64], firstp_s[8][64];
  __shared__ int lastn_s[8][64], firstn_s[8][64];
  const int b  = blockIdx.x >> 2;
  const int j0 = (blockIdx.x & 3) << 6;
  const int w  = threadIdx.x >> 6;
  const int l  = threadIdx.x & 63;
  const int j  = j0 + l;
  const int r0 = w << 5;

  int dp = SCAN_INIT, dn = SCAN_INIT;
  int firstp = BIGR, lastp = -BIGR, firstn = BIGR, lastn = -BIGR;
  #pragma unroll 4
  for (int i = 0; i < 32; ++i){
    const int gi = r0 + i;
    const float tv = tgt[(b*HH + gi)*WW + j];
    const bool s = tv > 0.5f;
    dp = s ? 0 : dp + 1;
    dn = s ? dn + 1 : 0;
    if (s){ lastp = gi; if (firstp == BIGR) firstp = gi; }
    else  { lastn = gi; if (firstn == BIGR) firstn = gi; }
    fwd_s[gi*64 + l] = ((unsigned)dp << 16) | (unsigned)dn;
  }
  lastp_s[w][l] = lastp; firstp_s[w][l] = firstp;
  lastn_s[w][l] = lastn; firstn_s[w][l] = firstn;
  __syncthreads();

  // cross-segment nearest-seed rows for this wave's segment
  int upP = -BIGR, dnP = BIGR, upN = -BIGR, dnN = BIGR;
  int allLastP = -BIGR, allLastN = -BIGR;
  #pragma unroll
  for (int s = 0; s < 8; ++s){
    const int lp = lastp_s[s][l], fp = firstp_s[s][l];
    const int ln = lastn_s[s][l], fn = firstn_s[s][l];
    allLastP = max(allLastP, lp); allLastN = max(allLastN, ln);
    if (s < w){ upP = max(upP, lp); upN = max(upN, ln); }
    if (s > w){ dnP = min(dnP, fp); dnN = min(dnN, fn); }
  }
  const bool colp = allLastP >= 0;
  const bool coln = allLastN >= 0;
  if (w == 0){
    unsigned long long bal = __ballot(colp);
    if (l == 0) hp_blk[blockIdx.x] = bal ? 1 : 0;
  }

  int bp = SCAN_INIT, bn = SCAN_INIT;
  #pragma unroll 4
  for (int i = 31; i >= 0; --i){
    const int gi = r0 + i;
    const unsigned f = fwd_s[gi*64 + l];
    const int fp = (int)(f >> 16), fn = (int)(f & 0xffffu);
    bp = (fp == 0) ? 0 : bp + 1;
    bn = (fn == 0) ? 0 : bn + 1;
    int Dp = min(min(fp, bp), min(gi - upP, dnP - gi));
    int Dn = min(min(fn, bn), min(gi - upN, dnN - gi));
    Dp = min(Dp, 512); Dn = min(Dn, 512);   // never binds when col has a seed
    const int o = (b*HH + gi)*WW + j;
    gA[o] = colp ? (float)(Dp*Dp) : INF_EDT;
    gB[o] = coln ? (float)(Dn*Dn) : INF_EDT;
  }
}

// -------------------------------------------------------------------------
// Fused row pass: per 4-row strip —
//  * EDT pass 2 (windowed min-plus: only |y-j| <= sqrt(g(x,y)) can improve;
//    clamp-overrun candidates never undercut the exact min)
//  * sobel magnitudes on sigmoid(x) and t (replicate pad; staged 6-row halo)
//  * focal + weighted-CE + boundary epilogue
// One scalar partial per block (final = (Σfoc+Σbce+Σbnd+Σedge)/NN).
// -------------------------------------------------------------------------
__global__ __launch_bounds__(256) void fused_row_k(const float* __restrict__ inp,
    const float* __restrict__ tgt, const float* __restrict__ gA, const float* __restrict__ gB,
    const int* __restrict__ hp_blk, float* __restrict__ part){
  __shared__ __align__(16) float ga_s[4][WW];
  __shared__ __align__(16) float gb_s[4][WW];
  __shared__ __align__(16) float ss[6][WW];   // sigmoid(x), rows x0-1..x0+4 clamped
  __shared__ __align__(16) float tt[6][WW];   // t, same rows
  __shared__ float red[4];
  const int b  = blockIdx.x >> 6;
  const int x0 = (blockIdx.x & 63) << 2;
  const int t  = threadIdx.x;
  const int g = t >> 6, l = t & 63;

  {
    const int l4 = l << 2;
    const int base = (b*HH + x0 + g)*WW + l4;
    *(float4*)&ga_s[g][l4] = *(const float4*)&gA[base];
    *(float4*)&gb_s[g][l4] = *(const float4*)&gB[base];
    for (int k = g; k < 6; k += 4){
      int gr = x0 - 1 + k; gr = gr < 0 ? 0 : (gr > HH-1 ? HH-1 : gr);
      const float4 xv = *(const float4*)&inp[(b*HH + gr)*WW + l4];
      const float4 tv = *(const float4*)&tgt[(b*HH + gr)*WW + l4];
      float4 sv; sv.x = sigmoidf(xv.x); sv.y = sigmoidf(xv.y);
      sv.z = sigmoidf(xv.z); sv.w = sigmoidf(xv.w);
      *(float4*)&ss[k][l4] = sv;
      *(float4*)&tt[k][l4] = tv;
    }
  }
  __syncthreads();

  const int y = t;
  const int hp_ = hp_blk[4*b] | hp_blk[4*b+1] | hp_blk[4*b+2] | hp_blk[4*b+3];
  const int cm = y ? y-1 : 0, cp = y < WW-1 ? y+1 : WW-1;

  // sliding 3x3 register window for sobel
  float a0m = ss[0][cm], a0c = ss[0][y], a0p = ss[0][cp];
  float a1m = ss[1][cm], a1c = ss[1][y], a1p = ss[1][cp];
  float b0m = tt[0][cm], b0c = tt[0][y], b0p = tt[0][cp];
  float b1m = tt[1][cm], b1c = tt[1][y], b1p = tt[1][cp];

  float acc = 0.0f;
  #pragma unroll
  for (int r = 0; r < 4; ++r){
    // ---- EDT pass 2, windowed ----
    float dpv = ga_s[r][y];
    float dnv = gb_s[r][y];
    int wm = (int)sqrtf(fmaxf(dpv, dnv)) + 1; if (wm > 255) wm = 255;
    for (int dj = 1; dj <= wm; dj += 4){
      #pragma unroll
      for (int u = 0; u < 4; ++u){
        const int d = dj + u;
        const float d2 = (float)(d*d);
        const int jl = (y - d) < 0   ? 0   : y - d;
        const int jr = (y + d) > 255 ? 255 : y + d;
        dpv = min3f(dpv, ga_s[r][jl] + d2, ga_s[r][jr] + d2);
        dnv = min3f(dnv, gb_s[r][jl] + d2, gb_s[r][jr] + d2);
      }
    }
    // ---- sobel (rows r..r+2 of staged halo) ----
    const float a2m = ss[r+2][cm], a2c = ss[r+2][y], a2p = ss[r+2][cp];
    const float b2m = tt[r+2][cm], b2c = tt[r+2][y], b2p = tt[r+2][cp];
    const float gxs = ((a0p-a0m) + 2.0f*(a1p-a1m) + (a2p-a2m)) * 0.125f;
    const float gys = ((a2m-a0m) + 2.0f*(a2c-a0c) + (a2p-a0p)) * 0.125f;
    const float mags = sqrtf(gxs*gxs + gys*gys + 1e-6f);
    const float gxt = ((b0p-b0m) + 2.0f*(b1p-b1m) + (b2p-b2m)) * 0.125f;
    const float gyt = ((b2m-b0m) + 2.0f*(b2c-b0c) + (b2p-b0p)) * 0.125f;
    const float magt = sqrtf(gxt*gxt + gyt*gyt + 1e-6f);
    acc += fabsf(mags - magt);
    a0m=a1m; a0c=a1c; a0p=a1p; a1m=a2m; a1c=a2c; a1p=a2p;
    b0m=b1m; b0c=b1c; b0p=b1p; b1m=b2m; b1c=b2c; b1p=b2p;

    // ---- focal / ce / boundary ----
    const float xv = inp[(b*HH + x0 + r)*WW + y];   // L1/L2-hot reload
    const float tv = tt[r+1][y];
    const float sg = ss[r+1][y];
    float sdf = sqrtf(dnv) - sqrtf(dpv);            // d_out - d_in
    sdf = hp_ ? sdf : 0.0f;
    acc += (sg - tv) * sdf;
    const float lp = logsigf(xv);
    const float ln = logsigf(-xv);
    const float bce = -(tv*lp + (1.0f - tv)*ln);
    const float pt = expf(-bce);
    const float om = 1.0f - pt;
    acc += 0.8f * om * om * bce;                    // focal (ALPHA=0.8, GAMMA=2)
    acc += bce;                                     // ce with POS_W=1 == bce
  }

  #pragma unroll
  for (int o = 32; o > 0; o >>= 1) acc += __shfl_down(acc, o);
  if (l == 0) red[g] = acc;
  __syncthreads();
  if (t == 0) part[blockIdx.x] = red[0]+red[1]+red[2]+red[3];
}

// Sum the 1024 block partials -> out.
__global__ __launch_bounds__(256) void finalize_k(const float* __restrict__ part,
                                                  float* __restrict__ out){
  __shared__ float red[4];
  const int t = threadIdx.x;
  float s = 0.0f;
  #pragma unroll
  for (int i = t; i < 1024; i += 256) s += part[i];
  #pragma unroll
  for (int o = 32; o > 0; o >>= 1) s += __shfl_down(s, o);
  if ((t & 63) == 0) red[t >> 6] = s;
  __syncthreads();
  if (t == 0) out[0] = (red[0]+red[1]+red[2]+red[3]) * (1.0f/(float)NN);
}

extern "C" void kernel_launch(void* const* d_in, const int* in_sizes, int n_in,
                              void* d_out, int out_size, void* d_ws, size_t ws_size,
                              hipStream_t stream){
  const float* inp = (const float*)d_in[0];
  const float* tgt = (const float*)d_in[1];
  float* out = (float*)d_out;
  float* gA   = (float*)d_ws;         // B*H*W fp32, seeds = pos
  float* gB   = gA + NN;              // B*H*W fp32, seeds = ~pos
  float* part = gB + NN;              // 1024 block partials
  int* hp_blk = (int*)(part + 1024);  // 64 per-scan-block pos flags

  edt_cols_scan<<<BB*4, 512, 0, stream>>>(tgt, gA, gB, hp_blk);
  fused_row_k<<<BB*(HH/4), 256, 0, stream>>>(inp, tgt, gA, gB, hp_blk, part);
  finalize_k<<<1, 256, 0, stream>>>(part, out);
}

// Round 11
// 86.323 us; speedup vs baseline: 3.1702x; 1.0781x over previous
//
#include <hip/hip_runtime.h>
#include <math.h>

#define BB 16
#define HH 256
#define WW 256
#define NN (BB*HH*WW)
#define SCAN_INIT 300
#define BIGR 100000

static __device__ constexpr float INF_EDT = 131072.0f; // H*H + W*W, exact in fp32

__device__ __forceinline__ float sigmoidf(float v){ return 1.0f/(1.0f+expf(-v)); }
// stable log_sigmoid(v) = min(v,0) - log1p(exp(-|v|))
__device__ __forceinline__ float logsigf(float v){
  return fminf(v, 0.0f) - log1pf(expf(-fabsf(v)));
}
__device__ __forceinline__ float min3f(float a, float b, float c){
  return fminf(fminf(a, b), c);   // clang fuses to v_min3_f32
}

// -------------------------------------------------------------------------
// Column EDT, segmented scan (exact for binary seeds).
// g(x,j) = Dcol(x,j)^2, Dcol = dist to nearest seed in column j, or 131072
// exactly if the column has none (brute force: INF + 0 at i=x).
// 256 blocks x 256 thr: block = (image b, 16-column group); thread =
// (col = t&15, seg = t>>4), seg scans rows [16*seg, 16*seg+16).
// Cross-segment: nearest seed above = max(last[s<seg]), below = min(first[s>seg]).
// hp_blk[blk] = any pos among this block's 16 columns (written every launch).
// Integer-valued fp32 -> bit-identical to the reference brute force.
// -------------------------------------------------------------------------
__global__ __launch_bounds__(256) void edt_cols_scan(const float* __restrict__ tgt,
                                                     float* __restrict__ gA,
                                                     float* __restrict__ gB,
                                                     int* __restrict__ hp_blk){
  __shared__ unsigned int fwd_s[HH*16];     // [row][col]: packed (dp<<16)|dn
  __shared__ int lastp_s[16*16], firstp_s[16*16];
  __shared__ int lastn_s[16*16], firstn_s[16*16];
  const int b   = blockIdx.x >> 4;
  const int j0  = (blockIdx.x & 15) << 4;
  const int t   = threadIdx.x;
  const int col = t & 15, seg = t >> 4;
  const int j = j0 + col, r0 = seg << 4;

  int dp = SCAN_INIT, dn = SCAN_INIT;
  int firstp = BIGR, lastp = -BIGR, firstn = BIGR, lastn = -BIGR;
  #pragma unroll 4
  for (int i = 0; i < 16; ++i){
    const int gi = r0 + i;
    const float tv = tgt[(b*HH + gi)*WW + j];
    const bool s = tv > 0.5f;
    dp = s ? 0 : dp + 1;
    dn = s ? dn + 1 : 0;
    if (s){ lastp = gi; if (firstp == BIGR) firstp = gi; }
    else  { lastn = gi; if (firstn == BIGR) firstn = gi; }
    fwd_s[gi*16 + col] = ((unsigned)dp << 16) | (unsigned)dn;
  }
  lastp_s[seg*16+col] = lastp; firstp_s[seg*16+col] = firstp;
  lastn_s[seg*16+col] = lastn; firstn_s[seg*16+col] = firstn;
  __syncthreads();

  // cross-segment nearest-seed rows for this thread's segment
  int upP=-BIGR, dnP=BIGR, upN=-BIGR, dnN=BIGR, allP=-BIGR, allN=-BIGR;
  #pragma unroll
  for (int s2 = 0; s2 < 16; ++s2){
    const int lp = lastp_s[s2*16+col], fp = firstp_s[s2*16+col];
    const int ln = lastn_s[s2*16+col], fn = firstn_s[s2*16+col];
    allP = max(allP, lp); allN = max(allN, ln);
    if (s2 < seg){ upP = max(upP, lp); upN = max(upN, ln); }
    if (s2 > seg){ dnP = min(dnP, fp); dnN = min(dnN, fn); }
  }
  const bool colp = allP >= 0;
  const bool coln = allN >= 0;
  if (t < 64){                     // wave 0 spans all 16 columns (x4 segs)
    unsigned long long bal = __ballot(colp);
    if (t == 0) hp_blk[blockIdx.x] = bal ? 1 : 0;
  }

  int bp = SCAN_INIT, bn = SCAN_INIT;
  #pragma unroll 4
  for (int i = 15; i >= 0; --i){
    const int gi = r0 + i;
    const unsigned f = fwd_s[gi*16 + col];
    const int fp = (int)(f >> 16), fn = (int)(f & 0xffffu);
    bp = (fp == 0) ? 0 : bp + 1;
    bn = (fn == 0) ? 0 : bn + 1;
    int Dp = min(min(fp, bp), min(gi - upP, dnP - gi));
    int Dn = min(min(fn, bn), min(gi - upN, dnN - gi));
    Dp = min(Dp, 512); Dn = min(Dn, 512);  // never binds when col has a seed
    const int o = (b*HH + gi)*WW + j;
    gA[o] = colp ? (float)(Dp*Dp) : INF_EDT;
    gB[o] = coln ? (float)(Dn*Dn) : INF_EDT;
  }
}

// -------------------------------------------------------------------------
// Fused row pass: per 4-row strip —
//  * EDT pass 2 (windowed min-plus: only |y-j| <= sqrt(g(x,y)) can improve;
//    clamp-overrun candidates never undercut the exact min)
//  * sobel magnitudes on sigmoid(x) and t (replicate pad; staged 6-row halo)
//  * focal + weighted-CE + boundary epilogue
// One scalar partial per block (final = (Σfoc+Σbce+Σbnd+Σedge)/NN).
// -------------------------------------------------------------------------
__global__ __launch_bounds__(256) void fused_row_k(const float* __restrict__ inp,
    const float* __restrict__ tgt, const float* __restrict__ gA, const float* __restrict__ gB,
    const int* __restrict__ hp_blk, float* __restrict__ part){
  __shared__ __align__(16) float ga_s[4][WW];
  __shared__ __align__(16) float gb_s[4][WW];
  __shared__ __align__(16) float ss[6][WW];   // sigmoid(x), rows x0-1..x0+4 clamped
  __shared__ __align__(16) float tt[6][WW];   // t, same rows
  __shared__ float red[4];
  const int b  = blockIdx.x >> 6;
  const int x0 = (blockIdx.x & 63) << 2;
  const int t  = threadIdx.x;
  const int g = t >> 6, l = t & 63;

  {
    const int l4 = l << 2;
    const int base = (b*HH + x0 + g)*WW + l4;
    *(float4*)&ga_s[g][l4] = *(const float4*)&gA[base];
    *(float4*)&gb_s[g][l4] = *(const float4*)&gB[base];
    for (int k = g; k < 6; k += 4){
      int gr = x0 - 1 + k; gr = gr < 0 ? 0 : (gr > HH-1 ? HH-1 : gr);
      const float4 xv = *(const float4*)&inp[(b*HH + gr)*WW + l4];
      const float4 tv = *(const float4*)&tgt[(b*HH + gr)*WW + l4];
      float4 sv; sv.x = sigmoidf(xv.x); sv.y = sigmoidf(xv.y);
      sv.z = sigmoidf(xv.z); sv.w = sigmoidf(xv.w);
      *(float4*)&ss[k][l4] = sv;
      *(float4*)&tt[k][l4] = tv;
    }
  }
  __syncthreads();

  int hp_ = 0;
  #pragma unroll
  for (int i = 0; i < 16; ++i) hp_ |= hp_blk[b*16 + i];

  const int y = t;
  const int cm = y ? y-1 : 0, cp = y < WW-1 ? y+1 : WW-1;

  // sliding 3x3 register window for sobel
  float a0m = ss[0][cm], a0c = ss[0][y], a0p = ss[0][cp];
  float a1m = ss[1][cm], a1c = ss[1][y], a1p = ss[1][cp];
  float b0m = tt[0][cm], b0c = tt[0][y], b0p = tt[0][cp];
  float b1m = tt[1][cm], b1c = tt[1][y], b1p = tt[1][cp];

  float acc = 0.0f;
  #pragma unroll
  for (int r = 0; r < 4; ++r){
    // ---- EDT pass 2, windowed ----
    float dpv = ga_s[r][y];
    float dnv = gb_s[r][y];
    int wm = (int)sqrtf(fmaxf(dpv, dnv)) + 1; if (wm > 255) wm = 255;
    for (int dj = 1; dj <= wm; dj += 4){
      #pragma unroll
      for (int u = 0; u < 4; ++u){
        const int d = dj + u;
        const float d2 = (float)(d*d);
        const int jl = (y - d) < 0   ? 0   : y - d;
        const int jr = (y + d) > 255 ? 255 : y + d;
        dpv = min3f(dpv, ga_s[r][jl] + d2, ga_s[r][jr] + d2);
        dnv = min3f(dnv, gb_s[r][jl] + d2, gb_s[r][jr] + d2);
      }
    }
    // ---- sobel (rows r..r+2 of staged halo) ----
    const float a2m = ss[r+2][cm], a2c = ss[r+2][y], a2p = ss[r+2][cp];
    const float b2m = tt[r+2][cm], b2c = tt[r+2][y], b2p = tt[r+2][cp];
    const float gxs = ((a0p-a0m) + 2.0f*(a1p-a1m) + (a2p-a2m)) * 0.125f;
    const float gys = ((a2m-a0m) + 2.0f*(a2c-a0c) + (a2p-a0p)) * 0.125f;
    const float mags = sqrtf(gxs*gxs + gys*gys + 1e-6f);
    const float gxt = ((b0p-b0m) + 2.0f*(b1p-b1m) + (b2p-b2m)) * 0.125f;
    const float gyt = ((b2m-b0m) + 2.0f*(b2c-b0c) + (b2p-b0p)) * 0.125f;
    const float magt = sqrtf(gxt*gxt + gyt*gyt + 1e-6f);
    acc += fabsf(mags - magt);
    a0m=a1m; a0c=a1c; a0p=a1p; a1m=a2m; a1c=a2c; a1p=a2p;
    b0m=b1m; b0c=b1c; b0p=b1p; b1m=b2m; b1c=b2c; b1p=b2p;

    // ---- focal / ce / boundary ----
    const float xv = inp[(b*HH + x0 + r)*WW + y];   // L1/L2-hot reload
    const float tv = tt[r+1][y];
    const float sg = ss[r+1][y];
    float sdf = sqrtf(dnv) - sqrtf(dpv);            // d_out - d_in
    sdf = hp_ ? sdf : 0.0f;
    acc += (sg - tv) * sdf;
    const float lp = logsigf(xv);
    const float ln = logsigf(-xv);
    const float bce = -(tv*lp + (1.0f - tv)*ln);
    const float pt = expf(-bce);
    const float om = 1.0f - pt;
    acc += 0.8f * om * om * bce;                    // focal (ALPHA=0.8, GAMMA=2)
    acc += bce;                                     // ce with POS_W=1 == bce
  }

  #pragma unroll
  for (int o = 32; o > 0; o >>= 1) acc += __shfl_down(acc, o);
  if (l == 0) red[g] = acc;
  __syncthreads();
  if (t == 0) part[blockIdx.x] = red[0]+red[1]+red[2]+red[3];
}

// Sum the 1024 block partials -> out.
__global__ __launch_bounds__(256) void finalize_k(const float* __restrict__ part,
                                                  float* __restrict__ out){
  __shared__ float red[4];
  const int t = threadIdx.x;
  float s = 0.0f;
  #pragma unroll
  for (int i = t; i < 1024; i += 256) s += part[i];
  #pragma unroll
  for (int o = 32; o > 0; o >>= 1) s += __shfl_down(s, o);
  if ((t & 63) == 0) red[t >> 6] = s;
  __syncthreads();
  if (t == 0) out[0] = (red[0]+red[1]+red[2]+red[3]) * (1.0f/(float)NN);
}

extern "C" void kernel_launch(void* const* d_in, const int* in_sizes, int n_in,
                              void* d_out, int out_size, void* d_ws, size_t ws_size,
                              hipStream_t stream){
  const float* inp = (const float*)d_in[0];
  const float* tgt = (const float*)d_in[1];
  float* out = (float*)d_out;
  float* gA   = (float*)d_ws;         // B*H*W fp32, seeds = pos
  float* gB   = gA + NN;              // B*H*W fp32, seeds = ~pos
  float* part = gB + NN;              // 1024 block partials
  int* hp_blk = (int*)(part + 1024);  // 256 per-scan-block pos flags

  edt_cols_scan<<<BB*16, 256, 0, stream>>>(tgt, gA, gB, hp_blk);
  fused_row_k<<<BB*(HH/4), 256, 0, stream>>>(inp, tgt, gA, gB, hp_blk, part);
  finalize_k<<<1, 256, 0, stream>>>(part, out);
}